// Round 20
// baseline (278.526 us; speedup 1.0000x reference)
//
#include <hip/hip_runtime.h>

#define M_TETS 10240
#define N_NODES 2048
#define NBUF 7
#define NBLK 10
#define NTHR 1024
#define SPIN_CAP 50000000

typedef float f32x4 __attribute__((ext_vector_type(4)));

// ws float offsets (global node stride 4 for aligned vload4 gathers)
#define BUFW 8192                          // 2048 nodes x 4 floats
#define OFF_VAL   12288                    // blk6: 6*2048 floats at 0
#define OFF_GDOT  (OFF_VAL + NBUF * BUFW)  // ring of NBUF buffers (0..6)
#define OFF_SLOT  (OFF_GDOT + 256)         // gdot: 2 sets x 2 comps x 64
#define WS_WORDS  (OFF_SLOT + 32)

// log(500), log(10000)
__device__ __constant__ float LOG_A_MIN_C = 6.2146080984221914f;
__device__ __constant__ float LOG_A_MAX_C = 9.2103403719761836f;

__device__ __forceinline__ void rel_fence() { __builtin_amdgcn_fence(__ATOMIC_RELEASE, "agent"); }
__device__ __forceinline__ void acq_fence() { __builtin_amdgcn_fence(__ATOMIC_ACQUIRE, "agent"); }
__device__ __forceinline__ unsigned aldu(const unsigned* p) {
    return __hip_atomic_load(p, __ATOMIC_RELAXED, __HIP_MEMORY_SCOPE_AGENT);
}
__device__ __forceinline__ float aldf(const float* p) {
    return __hip_atomic_load(p, __ATOMIC_RELAXED, __HIP_MEMORY_SCOPE_AGENT);
}
__device__ __forceinline__ void astf(float* p, float v) {
    __hip_atomic_store(p, v, __ATOMIC_RELAXED, __HIP_MEMORY_SCOPE_AGENT);
}
__device__ __forceinline__ void astu(unsigned* p, unsigned v) {
    __hip_atomic_store(p, v, __ATOMIC_RELAXED, __HIP_MEMORY_SCOPE_AGENT);
}

// coherence-point 16B load (R12/R14-proven across XCDs, no fences needed)
__device__ __forceinline__ f32x4 vload4(const float* p) {
    return *(volatile const f32x4*)p;
}

// Flag barrier. FULL=true: full release/acquire fences (setup only).
// FULL=false: fence-free — in-loop cross-block data moves via agent atomics /
// volatile ops at the coherence point; release = s_waitcnt vmcnt(0).
template<bool FULL>
__device__ __forceinline__ void flag_bar(unsigned* slots, unsigned tgt) {
    if (FULL) rel_fence();
    else asm volatile("s_waitcnt vmcnt(0)" ::: "memory");
    __syncthreads();
    if (threadIdx.x == 0) astu(&slots[blockIdx.x], tgt);
    if (threadIdx.x < NBLK) {
        int guard = 0;
        while (aldu(&slots[threadIdx.x]) < tgt && ++guard < SPIN_CAP) {}
    }
    __syncthreads();
    if (FULL) acq_fence();
    else asm volatile("" ::: "memory");
}

__device__ __forceinline__ void bfly2(float& a, float& b) {
#pragma unroll
    for (int off = 32; off > 0; off >>= 1) {
        a += __shfl_xor(a, off);
        b += __shfl_xor(b, off);
    }
}

// symmetric 3x3 apply: s6 = [00,01,02,11,12,22]
__device__ __forceinline__ void sym_apply(const float* s6, const float* v, float* out) {
    out[0] = s6[0]*v[0] + s6[1]*v[1] + s6[2]*v[2];
    out[1] = s6[1]*v[0] + s6[3]*v[1] + s6[4]*v[2];
    out[2] = s6[2]*v[0] + s6[4]*v[1] + s6[5]*v[2];
}

__device__ __forceinline__ void sym_inv(const float* s, float* o) {
    float a = s[0], b = s[1], c = s[2], d = s[3], e = s[4], f = s[5];
    float C00 = d*f - e*e, C01 = c*e - b*f, C02 = b*e - c*d;
    float id = 1.0f / (a*C00 + b*C01 + c*C02);
    o[0] = C00*id; o[1] = C01*id; o[2] = C02*id;
    o[3] = (a*f - c*c)*id; o[4] = (b*c - a*e)*id; o[5] = (a*d - b*b)*id;
}

__global__ void __launch_bounds__(NTHR, 1) pcg_kernel(
    const float* __restrict__ theta, const float* __restrict__ delta,
    const float* __restrict__ ra, const float* __restrict__ rs, const float* __restrict__ rv,
    const float* __restrict__ vol, const float* __restrict__ bvec,
    const int* __restrict__ tets, const int* __restrict__ boundary,
    float* __restrict__ xout, float* __restrict__ ws)
{
    const int tid = blockIdx.x * NTHR + threadIdx.x;   // element id, 10240 total
    const int lane = threadIdx.x & 63;
    const int wv = threadIdx.x >> 6;

    // LDS: S1 uses stride-7 (32-bank-spread) 7*2048=14336; phases use stride-3 6144.
    __shared__ float lds[14336];
    __shared__ float sred[8];
    __shared__ float sd[2];

    float*    blk6  = ws;
    float*    val   = ws + OFF_VAL;
    float*    gdot  = ws + OFF_GDOT;
    unsigned* slots = (unsigned*)(ws + OFF_SLOT);

    // ---- element data -> registers ----
    float A[3][12], S[3][12], V[12];
    int nd4[4];
    float cae, cse, cve;
    {
        const int e = tid;
#pragma unroll
        for (int a = 0; a < 3; a++)
#pragma unroll
            for (int i = 0; i < 12; i++) {
                A[a][i] = ra[e * 36 + a * 12 + i];
                S[a][i] = rs[e * 36 + a * 12 + i];
            }
#pragma unroll
        for (int i = 0; i < 12; i++) V[i] = rv[e * 12 + i];
        const int4 t = reinterpret_cast<const int4*>(tets)[e];
        nd4[0] = t.x; nd4[1] = t.y; nd4[2] = t.z; nd4[3] = t.w;
        float la = theta[0] + delta[e];
        la = fminf(fmaxf(la, LOG_A_MIN_C), LOG_A_MAX_C);
        float al = expf(la);
        float v = vol[e];
        cae = v * al; cse = 2.0f * v * al; cve = 8.0f * v * al;
    }

    auto matvec = [&](const float* pe, float* y) {
#pragma unroll
        for (int t = 0; t < 12; t++) y[t] = 0.f;
#pragma unroll
        for (int a = 0; a < 3; a++) {
            float qa = 0.f, qs = 0.f;
#pragma unroll
            for (int t = 0; t < 12; t++) { qa += A[a][t] * pe[t]; qs += S[a][t] * pe[t]; }
            qa *= cae; qs *= cse;
#pragma unroll
            for (int t = 0; t < 12; t++) y[t] += qa * A[a][t] + qs * S[a][t];
        }
        float qv = 0.f;
#pragma unroll
        for (int t = 0; t < 12; t++) qv += V[t] * pe[t];
        qv *= cve;
#pragma unroll
        for (int t = 0; t < 12; t++) y[t] += qv * V[t];
    };

    // LDS-aggregated scatter of y[12] into ring buffer vS (called per phase)
    auto lds_scatter = [&](const float* y, float* vS) {
#pragma unroll
        for (int kk = 0; kk < 4; kk++)
#pragma unroll
            for (int c = 0; c < 3; c++)
                atomicAdd(&lds[3 * nd4[kk] + c], y[3*kk+c]);
        __syncthreads();
        for (int i = threadIdx.x; i < N_NODES; i += NTHR) {
            float a0 = lds[3*i], a1 = lds[3*i+1], a2 = lds[3*i+2];
            if (a0 != 0.f || a1 != 0.f || a2 != 0.f) {
                atomicAdd(&vS[4*i+0], a0);
                atomicAdd(&vS[4*i+1], a1);
                atomicAdd(&vS[4*i+2], a2);
            }
        }
    };

    // ---- S1: per-node 3x3 blocks, LDS-aggregated (stride 7), export to blk6 ----
    for (int i = threadIdx.x; i < 14336; i += NTHR) lds[i] = 0.f;
    __syncthreads();
#pragma unroll
    for (int k = 0; k < 4; k++) {
        float b6[6] = {0,0,0,0,0,0};
#pragma unroll
        for (int a = 0; a < 3; a++) {
            float x0 = A[a][3*k], x1 = A[a][3*k+1], x2 = A[a][3*k+2];
            float s0 = S[a][3*k], s1 = S[a][3*k+1], s2 = S[a][3*k+2];
            b6[0] += cae*x0*x0 + cse*s0*s0;
            b6[1] += cae*x0*x1 + cse*s0*s1;
            b6[2] += cae*x0*x2 + cse*s0*s2;
            b6[3] += cae*x1*x1 + cse*s1*s1;
            b6[4] += cae*x1*x2 + cse*s1*s2;
            b6[5] += cae*x2*x2 + cse*s2*s2;
        }
        float v0 = V[3*k], v1 = V[3*k+1], v2 = V[3*k+2];
        b6[0] += cve*v0*v0; b6[1] += cve*v0*v1; b6[2] += cve*v0*v2;
        b6[3] += cve*v1*v1; b6[4] += cve*v1*v2; b6[5] += cve*v2*v2;
#pragma unroll
        for (int j = 0; j < 6; j++) atomicAdd(&lds[7 * nd4[k] + j], b6[j]);
    }
    __syncthreads();
    for (int i = threadIdx.x; i < N_NODES; i += NTHR) {
        bool nz = false;
#pragma unroll
        for (int j = 0; j < 6; j++) nz = nz || (lds[7*i+j] != 0.f);
        if (nz) {
#pragma unroll
            for (int j = 0; j < 6; j++) atomicAdd(&blk6[6*i+j], lds[7*i+j]);
        }
    }
    flag_bar<true>(slots, 1);

    // ---- local inverses: elements (masked, per node) and owners ----
    float ib[4][6], nmask4[4];
#pragma unroll
    for (int k = 0; k < 4; k++) {
        float bm = boundary[nd4[k]] ? 0.f : 1.f;
        nmask4[k] = bm;
        float s6[6];
#pragma unroll
        for (int j = 0; j < 6; j++) s6[j] = blk6[nd4[k]*6 + j];
        float iv[6];
        sym_inv(s6, iv);
#pragma unroll
        for (int j = 0; j < 6; j++) ib[k][j] = iv[j] * bm;
    }

    const int nbase = ((int)blockIdx.x * N_NODES) / NBLK;
    const int ncnt  = (((int)blockIdx.x + 1) * N_NODES) / NBLK - nbase;
    const bool ownval = ((int)threadIdx.x < ncnt);
    const int own = nbase + (int)threadIdx.x;
    float iO[6] = {0,0,0,0,0,0};
    float maskO = 0.f;
    float xO[3]={0,0,0}, rO[3]={0,0,0}, uO[3]={0,0,0}, wO[3]={0,0,0}, mO[3]={0,0,0};
    float zO[3]={0,0,0}, qO[3]={0,0,0}, pO[3]={0,0,0}, sO[3]={0,0,0};
    if (ownval) {
        maskO = boundary[own] ? 0.f : 1.f;
        float s6[6];
#pragma unroll
        for (int j = 0; j < 6; j++) s6[j] = blk6[own*6 + j];
        float iv[6];
        sym_inv(s6, iv);
#pragma unroll
        for (int j = 0; j < 6; j++) iO[j] = iv[j] * maskO;
#pragma unroll
        for (int j = 0; j < 3; j++) rO[j] = bvec[3*own+j] * maskO;
        sym_apply(iO, rO, uO);
    }

    // owner dot publish across 4 owner-waves
    auto owner_pub = [&](float gn, float dn, float* gd_pub) {
        bfly2(gn, dn);
        if (lane == 0 && wv < 4) { sred[2*wv] = gn; sred[2*wv+1] = dn; }
        __syncthreads();
        if (threadIdx.x == 0) {
            astf(&gd_pub[blockIdx.x], sred[0]+sred[2]+sred[4]+sred[6]);
            astf(&gd_pub[64 + blockIdx.x], sred[1]+sred[3]+sred[5]+sred[7]);
        }
    };

    // ---- phase -1: scatter A*u0 into ring[0] ----
    {
        float u0e[12];
#pragma unroll
        for (int k = 0; k < 4; k++) {
            float bb[3] = { bvec[3*nd4[k]], bvec[3*nd4[k]+1], bvec[3*nd4[k]+2] };
            sym_apply(ib[k], bb, &u0e[3*k]);
        }
        float y[12];
        matvec(u0e, y);
        for (int i = threadIdx.x; i < 6144; i += NTHR) lds[i] = 0.f;
        __syncthreads();
        lds_scatter(y, val);                 // ring[0]
    }
    flag_bar<false>(slots, 2);

    // ---- phase 0: consume ring[0]; init replicas/owner; scatter A*m0 -> ring[1]; dots(0) ----
    float w_e[12], z_e[12];
    {
        const float* vR = val;               // ring[0]
        float me[12];
#pragma unroll
        for (int kk = 0; kk < 4; kk++) {
            f32x4 t = vload4(&vR[4*nd4[kk]]);
            w_e[3*kk]   = t[0] * nmask4[kk];
            w_e[3*kk+1] = t[1] * nmask4[kk];
            w_e[3*kk+2] = t[2] * nmask4[kk];
            z_e[3*kk] = 0.f; z_e[3*kk+1] = 0.f; z_e[3*kk+2] = 0.f;
        }
        for (int i = threadIdx.x; i < 6144; i += NTHR) lds[i] = 0.f;
#pragma unroll
        for (int kk = 0; kk < 4; kk++) sym_apply(ib[kk], &w_e[3*kk], &me[3*kk]);
        float y[12];
        matvec(me, y);
        __syncthreads();                     // zero complete
        lds_scatter(y, val + BUFW);          // ring[1]

        float gn = 0.f, dn = 0.f;
        if (ownval) {
            f32x4 t = vload4(&vR[4*own]);
            wO[0] = t[0] * maskO; wO[1] = t[1] * maskO; wO[2] = t[2] * maskO;
            sym_apply(iO, wO, mO);
#pragma unroll
            for (int j = 0; j < 3; j++) {
                gn += rO[j]*uO[j]; dn += wO[j]*uO[j];
            }
        }
        owner_pub(gn, dn, gdot);             // dots(0) -> set 0
    }
    flag_bar<false>(slots, 3);

    // ---- full iterations k = 1..5 ----
    float gp = 1.f, ap = 1.f;
    unsigned tgt = 4;

    for (int k = 1; k <= 5; k++) {
        const float* vR = val + k * BUFW;

        // early gathers (coherence point; overlap zero + dot completion)
        float ne[12];
#pragma unroll
        for (int kk = 0; kk < 4; kk++) {
            f32x4 t = vload4(&vR[4*nd4[kk]]);
            ne[3*kk]   = t[0] * nmask4[kk];
            ne[3*kk+1] = t[1] * nmask4[kk];
            ne[3*kk+2] = t[2] * nmask4[kk];
        }
        float nO[3] = {0,0,0};
        if (ownval) {
            f32x4 t = vload4(&vR[4*own]);
            nO[0] = t[0] * maskO; nO[1] = t[1] * maskO; nO[2] = t[2] * maskO;
        }

        // zero LDS phase region
        for (int i = threadIdx.x; i < 6144; i += NTHR) lds[i] = 0.f;

        // cross-block dot completion (wave 0; unused slots are zero)
        if (threadIdx.x < 64) {
            const float* dbase = gdot + ((k - 1) & 1) * 128;
            float g0 = aldf(&dbase[lane]);
            float d0 = aldf(&dbase[64 + lane]);
            bfly2(g0, d0);
            if (threadIdx.x == 0) { sd[0] = g0; sd[1] = d0; }
        }
        __syncthreads();                     // sd + zero complete
        float gam = sd[0], del = sd[1];

        float beta  = (k == 1) ? 0.f : ((gp != 0.f) ? gam / gp : 0.f);
        float den   = (k == 1) ? del : (del - beta * gam / ((ap != 0.f) ? ap : 1.f));
        float alpha = (den != 0.f) ? gam / den : 0.f;

        // element replica update + matvec + LDS-aggregated scatter -> ring[k+1]
        {
#pragma unroll
            for (int t = 0; t < 12; t++) {
                z_e[t] = ne[t] + beta * z_e[t];
                w_e[t] -= alpha * z_e[t];
            }
            float me[12];
#pragma unroll
            for (int kk = 0; kk < 4; kk++) sym_apply(ib[kk], &w_e[3*kk], &me[3*kk]);
            float y[12];
            matvec(me, y);
            lds_scatter(y, val + (k + 1) * BUFW);
        }

        // owner recurrences + dot publish
        float gn = 0.f, dn = 0.f;
        if (ownval) {
#pragma unroll
            for (int j = 0; j < 3; j++) {
                zO[j] = nO[j] + beta * zO[j];
                qO[j] = mO[j] + beta * qO[j];
                pO[j] = uO[j] + beta * pO[j];
                sO[j] = wO[j] + beta * sO[j];
                xO[j] += alpha * pO[j];
                rO[j] -= alpha * sO[j];
                uO[j] -= alpha * qO[j];
                wO[j] -= alpha * zO[j];
            }
            sym_apply(iO, wO, mO);
#pragma unroll
            for (int j = 0; j < 3; j++) {
                gn += rO[j]*uO[j]; dn += wO[j]*uO[j];
            }
        }
        owner_pub(gn, dn, gdot + (k & 1) * 128);

        gp = gam; ap = alpha;
        flag_bar<false>(slots, tgt++);
    }

    // ---- k = 6: owner-only ----
    {
        if (threadIdx.x < 64) {
            const float* dbase = gdot + 128;   // (6-1)&1 = 1
            float g0 = aldf(&dbase[lane]);
            float d0 = aldf(&dbase[64 + lane]);
            bfly2(g0, d0);
            if (threadIdx.x == 0) { sd[0] = g0; sd[1] = d0; }
        }
        __syncthreads();
        float gam = sd[0], del = sd[1];
        float beta  = (gp != 0.f) ? gam / gp : 0.f;
        float den   = del - beta * gam / ((ap != 0.f) ? ap : 1.f);
        float alpha = (den != 0.f) ? gam / den : 0.f;

        float gn = 0.f, dn = 0.f;
        if (ownval) {
            f32x4 t = vload4(&val[6 * BUFW + 4*own]);
            float nO[3] = { t[0] * maskO, t[1] * maskO, t[2] * maskO };
#pragma unroll
            for (int j = 0; j < 3; j++) {
                zO[j] = nO[j] + beta * zO[j];
                qO[j] = mO[j] + beta * qO[j];
                pO[j] = uO[j] + beta * pO[j];
                sO[j] = wO[j] + beta * sO[j];
                xO[j] += alpha * pO[j];
                rO[j] -= alpha * sO[j];
                uO[j] -= alpha * qO[j];
                wO[j] -= alpha * zO[j];
            }
#pragma unroll
            for (int j = 0; j < 3; j++) {
                gn += rO[j]*uO[j]; dn += wO[j]*uO[j];
            }
        }
        owner_pub(gn, dn, gdot);               // dots(6) -> set 0
        gp = gam; ap = alpha;
        flag_bar<false>(slots, tgt++);
    }

    // ---- k = 7: finalize (only p,x live) ----
    {
        if (threadIdx.x < 64) {
            const float* dbase = gdot;          // (7-1)&1 = 0
            float g0 = aldf(&dbase[lane]);
            float d0 = aldf(&dbase[64 + lane]);
            bfly2(g0, d0);
            if (threadIdx.x == 0) { sd[0] = g0; sd[1] = d0; }
        }
        __syncthreads();
        float gam = sd[0], del = sd[1];
        float beta  = (gp != 0.f) ? gam / gp : 0.f;
        float den   = del - beta * gam / ((ap != 0.f) ? ap : 1.f);
        float alpha = (den != 0.f) ? gam / den : 0.f;

        if (ownval) {
#pragma unroll
            for (int j = 0; j < 3; j++) {
                pO[j] = uO[j] + beta * pO[j];
                xO[j] += alpha * pO[j];
            }
#pragma unroll
            for (int j = 0; j < 3; j++) xout[3*own+j] = xO[j];
        }
    }
}

extern "C" void kernel_launch(void* const* d_in, const int* in_sizes, int n_in,
                              void* d_out, int out_size, void* d_ws, size_t ws_size,
                              hipStream_t stream) {
    const float* theta = (const float*)d_in[0];
    const float* delta = (const float*)d_in[1];
    const float* ra    = (const float*)d_in[2];
    const float* rs    = (const float*)d_in[3];
    const float* rv    = (const float*)d_in[4];
    const float* vol   = (const float*)d_in[5];
    const float* b     = (const float*)d_in[6];
    const int* tets    = (const int*)d_in[7];
    const int* boundary = (const int*)d_in[8];
    float* x = (float*)d_out;
    float* ws = (float*)d_ws;

    hipMemsetAsync(ws, 0, WS_WORDS * sizeof(float), stream);
    pcg_kernel<<<dim3(NBLK), dim3(NTHR), 0, stream>>>(theta, delta, ra, rs, rv, vol, b,
                                                      tets, boundary, x, ws);
}

// Round 21
// 105.469 us; speedup vs baseline: 2.6408x; 2.6408x over previous
//
#include <hip/hip_runtime.h>

#define M_TETS 10240
#define N_NODES 2048
#define NBUF 6
#define NBLK 32
#define NTHR 320
#define SPIN_CAP 50000000

typedef float f32x4 __attribute__((ext_vector_type(4)));

// ws float offsets (16B node stride)
#define BUFW 8192                          // 2048 nodes x 4 floats
#define OFF_VAL   12288                    // blk6: 6*2048 floats at 0
#define OFF_GDOT  (OFF_VAL + NBUF * BUFW)  // ring of NBUF buffers (0..5)
#define OFF_SLOT  (OFF_GDOT + 256)         // gdot: 2 sets x 2 comps x 64
#define WS_WORDS  (OFF_SLOT + 32)

// log(500), log(10000)
__device__ __constant__ float LOG_A_MIN_C = 6.2146080984221914f;
__device__ __constant__ float LOG_A_MAX_C = 9.2103403719761836f;

__device__ __forceinline__ void rel_fence() { __builtin_amdgcn_fence(__ATOMIC_RELEASE, "agent"); }
__device__ __forceinline__ void acq_fence() { __builtin_amdgcn_fence(__ATOMIC_ACQUIRE, "agent"); }
__device__ __forceinline__ unsigned aldu(const unsigned* p) {
    return __hip_atomic_load(p, __ATOMIC_RELAXED, __HIP_MEMORY_SCOPE_AGENT);
}
__device__ __forceinline__ float aldf(const float* p) {
    return __hip_atomic_load(p, __ATOMIC_RELAXED, __HIP_MEMORY_SCOPE_AGENT);
}
__device__ __forceinline__ void astf(float* p, float v) {
    __hip_atomic_store(p, v, __ATOMIC_RELAXED, __HIP_MEMORY_SCOPE_AGENT);
}
__device__ __forceinline__ void astu(unsigned* p, unsigned v) {
    __hip_atomic_store(p, v, __ATOMIC_RELAXED, __HIP_MEMORY_SCOPE_AGENT);
}

// coherence-point 16B load (R12/R14-proven: observes remote agent-atomic
// stores across XCDs with no fences)
__device__ __forceinline__ f32x4 vload4(const float* p) {
    return *(volatile const f32x4*)p;
}

// Flag barrier. FULL=true: full release/acquire fences (setup only).
// FULL=false: fence-free — in-loop writes are all agent atomics (performed at
// the coherence point); release ordering = s_waitcnt vmcnt(0) before the flag
// store; reads after the barrier use volatile/atomic ops, so no inv needed.
template<bool FULL>
__device__ __forceinline__ void flag_bar(unsigned* slots, unsigned tgt) {
    if (FULL) rel_fence();
    else asm volatile("s_waitcnt vmcnt(0)" ::: "memory");
    __syncthreads();
    if (threadIdx.x == 0) astu(&slots[blockIdx.x], tgt);
    if (threadIdx.x < NBLK) {
        int guard = 0;
        while (aldu(&slots[threadIdx.x]) < tgt && ++guard < SPIN_CAP) {}
    }
    __syncthreads();
    if (FULL) acq_fence();
    else asm volatile("" ::: "memory");
}

__device__ __forceinline__ void bfly2(float& a, float& b) {
#pragma unroll
    for (int off = 32; off > 0; off >>= 1) {
        a += __shfl_xor(a, off);
        b += __shfl_xor(b, off);
    }
}

// symmetric 3x3 apply: s6 = [00,01,02,11,12,22]
__device__ __forceinline__ void sym_apply(const float* s6, const float* v, float* out) {
    out[0] = s6[0]*v[0] + s6[1]*v[1] + s6[2]*v[2];
    out[1] = s6[1]*v[0] + s6[3]*v[1] + s6[4]*v[2];
    out[2] = s6[2]*v[0] + s6[4]*v[1] + s6[5]*v[2];
}

__device__ __forceinline__ void sym_inv(const float* s, float* o) {
    float a = s[0], b = s[1], c = s[2], d = s[3], e = s[4], f = s[5];
    float C00 = d*f - e*e, C01 = c*e - b*f, C02 = b*e - c*d;
    float id = 1.0f / (a*C00 + b*C01 + c*C02);
    o[0] = C00*id; o[1] = C01*id; o[2] = C02*id;
    o[3] = (a*f - c*c)*id; o[4] = (b*c - a*e)*id; o[5] = (a*d - b*b)*id;
}

__global__ void __launch_bounds__(NTHR, 1) pcg_kernel(
    const float* __restrict__ theta, const float* __restrict__ delta,
    const float* __restrict__ ra, const float* __restrict__ rs, const float* __restrict__ rv,
    const float* __restrict__ vol, const float* __restrict__ bvec,
    const int* __restrict__ tets, const int* __restrict__ boundary,
    float* __restrict__ xout, float* __restrict__ ws)
{
    const int tid = blockIdx.x * NTHR + threadIdx.x;   // element id, 10240 total
    const int lane = threadIdx.x & 63;
    __shared__ float sd[2];

    float*    blk6  = ws;
    float*    val   = ws + OFF_VAL;
    float*    gdot  = ws + OFF_GDOT;
    unsigned* slots = (unsigned*)(ws + OFF_SLOT);

    // ---- element data -> registers (ws pre-zeroed by hipMemsetAsync) ----
    float A[3][12], S[3][12], V[12];
    int nd4[4];
    float cae, cse, cve;
    {
        const int e = tid;
#pragma unroll
        for (int a = 0; a < 3; a++)
#pragma unroll
            for (int i = 0; i < 12; i++) {
                A[a][i] = ra[e * 36 + a * 12 + i];
                S[a][i] = rs[e * 36 + a * 12 + i];
            }
#pragma unroll
        for (int i = 0; i < 12; i++) V[i] = rv[e * 12 + i];
        const int4 t = reinterpret_cast<const int4*>(tets)[e];
        nd4[0] = t.x; nd4[1] = t.y; nd4[2] = t.z; nd4[3] = t.w;
        float la = theta[0] + delta[e];
        la = fminf(fmaxf(la, LOG_A_MIN_C), LOG_A_MAX_C);
        float al = expf(la);
        float v = vol[e];
        cae = v * al; cse = 2.0f * v * al; cve = 8.0f * v * al;
    }

    auto matvec = [&](const float* pe, float* y) {
#pragma unroll
        for (int t = 0; t < 12; t++) y[t] = 0.f;
#pragma unroll
        for (int a = 0; a < 3; a++) {
            float qa = 0.f, qs = 0.f;
#pragma unroll
            for (int t = 0; t < 12; t++) { qa += A[a][t] * pe[t]; qs += S[a][t] * pe[t]; }
            qa *= cae; qs *= cse;
#pragma unroll
            for (int t = 0; t < 12; t++) y[t] += qa * A[a][t] + qs * S[a][t];
        }
        float qv = 0.f;
#pragma unroll
        for (int t = 0; t < 12; t++) qv += V[t] * pe[t];
        qv *= cve;
#pragma unroll
        for (int t = 0; t < 12; t++) y[t] += qv * V[t];
    };

    // ---- S1: accumulate symmetric per-node 3x3 blocks of K ----
#pragma unroll
    for (int k = 0; k < 4; k++) {
        float b6[6] = {0,0,0,0,0,0};
#pragma unroll
        for (int a = 0; a < 3; a++) {
            float x0 = A[a][3*k], x1 = A[a][3*k+1], x2 = A[a][3*k+2];
            float s0 = S[a][3*k], s1 = S[a][3*k+1], s2 = S[a][3*k+2];
            b6[0] += cae*x0*x0 + cse*s0*s0;
            b6[1] += cae*x0*x1 + cse*s0*s1;
            b6[2] += cae*x0*x2 + cse*s0*s2;
            b6[3] += cae*x1*x1 + cse*s1*s1;
            b6[4] += cae*x1*x2 + cse*s1*s2;
            b6[5] += cae*x2*x2 + cse*s2*s2;
        }
        float v0 = V[3*k], v1 = V[3*k+1], v2 = V[3*k+2];
        b6[0] += cve*v0*v0; b6[1] += cve*v0*v1; b6[2] += cve*v0*v2;
        b6[3] += cve*v1*v1; b6[4] += cve*v1*v2; b6[5] += cve*v2*v2;
#pragma unroll
        for (int j = 0; j < 6; j++) atomicAdd(&blk6[nd4[k]*6 + j], b6[j]);
    }
    flag_bar<true>(slots, 1);

    // ---- local inverses: elements (masked, per node) and owners ----
    float ib[4][6], nmask4[4];
#pragma unroll
    for (int k = 0; k < 4; k++) {
        float bm = boundary[nd4[k]] ? 0.f : 1.f;
        nmask4[k] = bm;
        float s6[6];
#pragma unroll
        for (int j = 0; j < 6; j++) s6[j] = blk6[nd4[k]*6 + j];
        float iv[6];
        sym_inv(s6, iv);
#pragma unroll
        for (int j = 0; j < 6; j++) ib[k][j] = iv[j] * bm;
    }

    const int own = blockIdx.x * 64 + threadIdx.x;   // exact: 32*64 = 2048
    const bool ownval = (threadIdx.x < 64);
    float iO[6] = {0,0,0,0,0,0};
    float maskO = 0.f;
    float xO[3]={0,0,0}, rO[3]={0,0,0}, uO[3]={0,0,0}, wO[3]={0,0,0}, mO[3]={0,0,0};
    float zO[3]={0,0,0}, qO[3]={0,0,0}, pO[3]={0,0,0}, sO[3]={0,0,0};
    if (ownval) {
        maskO = boundary[own] ? 0.f : 1.f;
        float s6[6];
#pragma unroll
        for (int j = 0; j < 6; j++) s6[j] = blk6[own*6 + j];
        float iv[6];
        sym_inv(s6, iv);
#pragma unroll
        for (int j = 0; j < 6; j++) iO[j] = iv[j] * maskO;
#pragma unroll
        for (int j = 0; j < 3; j++) rO[j] = bvec[3*own+j] * maskO;
        sym_apply(iO, rO, uO);
    }

    // ---- phase -1: scatter A*u0 into ring[0] ----
    {
        float u0e[12];
#pragma unroll
        for (int k = 0; k < 4; k++) {
            float bb[3] = { bvec[3*nd4[k]], bvec[3*nd4[k]+1], bvec[3*nd4[k]+2] };
            sym_apply(ib[k], bb, &u0e[3*k]);
        }
        float y[12];
        matvec(u0e, y);
        float* v0 = val;                     // ring[0]
#pragma unroll
        for (int kk = 0; kk < 4; kk++)
#pragma unroll
            for (int c = 0; c < 3; c++) atomicAdd(&v0[4*nd4[kk]+c], y[3*kk+c]);
    }
    flag_bar<false>(slots, 2);

    // ---- phase 0: consume ring[0] (w0); init replicas/owner; scatter A*m0 -> ring[1] ----
    float w_e[12], z_e[12];
    {
        const float* vR = val;               // ring[0]
#pragma unroll
        for (int kk = 0; kk < 4; kk++) {
            f32x4 t = vload4(&vR[4*nd4[kk]]);
            w_e[3*kk]   = t[0] * nmask4[kk];
            w_e[3*kk+1] = t[1] * nmask4[kk];
            w_e[3*kk+2] = t[2] * nmask4[kk];
            z_e[3*kk] = 0.f; z_e[3*kk+1] = 0.f; z_e[3*kk+2] = 0.f;
        }
        float me[12];
#pragma unroll
        for (int kk = 0; kk < 4; kk++) sym_apply(ib[kk], &w_e[3*kk], &me[3*kk]);
        float y[12];
        matvec(me, y);
        float* vS = val + BUFW;              // ring[1]
#pragma unroll
        for (int kk = 0; kk < 4; kk++)
#pragma unroll
            for (int c = 0; c < 3; c++) atomicAdd(&vS[4*nd4[kk]+c], y[3*kk+c]);

        if (ownval) {
            float gn = 0.f, dn = 0.f;
            f32x4 t = vload4(&vR[4*own]);
            wO[0] = t[0] * maskO; wO[1] = t[1] * maskO; wO[2] = t[2] * maskO;
            sym_apply(iO, wO, mO);
#pragma unroll
            for (int j = 0; j < 3; j++) {
                gn += rO[j]*uO[j]; dn += wO[j]*uO[j];
            }
            bfly2(gn, dn);
            if (threadIdx.x == 0) {
                astf(&gdot[blockIdx.x], gn);
                astf(&gdot[64 + blockIdx.x], dn);
            }
        }
    }
    flag_bar<false>(slots, 3);

    // ---- full iterations k = 1..4 (scatter ring[k+1], publish dots(k)) ----
    float gp = 1.f, ap = 1.f;
    unsigned tgt = 4;

    for (int k = 1; k <= 4; k++) {
        const float* vR = val + k * BUFW;

        // gather n early (coherence point; overlaps dot completion)
        float ne[12];
#pragma unroll
        for (int kk = 0; kk < 4; kk++) {
            f32x4 t = vload4(&vR[4*nd4[kk]]);
            ne[3*kk]   = t[0] * nmask4[kk];
            ne[3*kk+1] = t[1] * nmask4[kk];
            ne[3*kk+2] = t[2] * nmask4[kk];
        }
        float nO[3] = {0,0,0};
        if (ownval) {
            f32x4 t = vload4(&vR[4*own]);
            nO[0] = t[0] * maskO; nO[1] = t[1] * maskO; nO[2] = t[2] * maskO;
        }

        // cross-block dot completion (wave 0; slots 32..63 are zero-padding)
        if (threadIdx.x < 64) {
            const float* dbase = gdot + ((k - 1) & 1) * 128;
            float g0 = aldf(&dbase[lane]);
            float d0 = aldf(&dbase[64 + lane]);
            bfly2(g0, d0);
            if (threadIdx.x == 0) { sd[0] = g0; sd[1] = d0; }
        }
        __syncthreads();
        float gam = sd[0], del = sd[1];

        float beta  = (k == 1) ? 0.f : ((gp != 0.f) ? gam / gp : 0.f);
        float den   = (k == 1) ? del : (del - beta * gam / ((ap != 0.f) ? ap : 1.f));
        float alpha = (den != 0.f) ? gam / den : 0.f;

        // element replica update + matvec + scatter into ring[k+1]
        {
#pragma unroll
            for (int t = 0; t < 12; t++) {
                z_e[t] = ne[t] + beta * z_e[t];
                w_e[t] -= alpha * z_e[t];
            }
            float me[12];
#pragma unroll
            for (int kk = 0; kk < 4; kk++) sym_apply(ib[kk], &w_e[3*kk], &me[3*kk]);
            float y[12];
            matvec(me, y);
            float* vS = val + (k + 1) * BUFW;
#pragma unroll
            for (int kk = 0; kk < 4; kk++)
#pragma unroll
                for (int c = 0; c < 3; c++) atomicAdd(&vS[4*nd4[kk]+c], y[3*kk+c]);
        }

        // owner recurrences + dot publish
        if (ownval) {
            float gn = 0.f, dn = 0.f;
#pragma unroll
            for (int j = 0; j < 3; j++) {
                zO[j] = nO[j] + beta * zO[j];
                qO[j] = mO[j] + beta * qO[j];
                pO[j] = uO[j] + beta * pO[j];
                sO[j] = wO[j] + beta * sO[j];
                xO[j] += alpha * pO[j];
                rO[j] -= alpha * sO[j];
                uO[j] -= alpha * qO[j];
                wO[j] -= alpha * zO[j];
            }
            sym_apply(iO, wO, mO);
#pragma unroll
            for (int j = 0; j < 3; j++) {
                gn += rO[j]*uO[j]; dn += wO[j]*uO[j];
            }
            bfly2(gn, dn);
            float* gd_pub = gdot + (k & 1) * 128;
            if (threadIdx.x == 0) {
                astf(&gd_pub[blockIdx.x], gn);
                astf(&gd_pub[64 + blockIdx.x], dn);
            }
        }

        gp = gam; ap = alpha;
        flag_bar<false>(slots, tgt++);
    }

    // ---- k = 5: owner-only (element scatter would feed only dead state) ----
    {
        // dot completion for dots(4) (set 0)
        if (threadIdx.x < 64) {
            const float* dbase = gdot;         // (5-1)&1 = 0
            float g0 = aldf(&dbase[lane]);
            float d0 = aldf(&dbase[64 + lane]);
            bfly2(g0, d0);
            if (threadIdx.x == 0) { sd[0] = g0; sd[1] = d0; }
        }
        __syncthreads();
        float gam = sd[0], del = sd[1];
        float beta  = (gp != 0.f) ? gam / gp : 0.f;
        float den   = del - beta * gam / ((ap != 0.f) ? ap : 1.f);
        float alpha = (den != 0.f) ? gam / den : 0.f;

        if (ownval) {
            f32x4 t = vload4(&val[5 * BUFW + 4*own]);
            float nO[3] = { t[0] * maskO, t[1] * maskO, t[2] * maskO };
            float gn = 0.f, dn = 0.f;
#pragma unroll
            for (int j = 0; j < 3; j++) {
                zO[j] = nO[j] + beta * zO[j];
                qO[j] = mO[j] + beta * qO[j];
                pO[j] = uO[j] + beta * pO[j];
                sO[j] = wO[j] + beta * sO[j];
                xO[j] += alpha * pO[j];
                rO[j] -= alpha * sO[j];
                uO[j] -= alpha * qO[j];
                wO[j] -= alpha * zO[j];
            }
#pragma unroll
            for (int j = 0; j < 3; j++) {
                gn += rO[j]*uO[j]; dn += wO[j]*uO[j];
            }
            bfly2(gn, dn);
            if (threadIdx.x == 0) {          // publish dots(5) -> set 1
                astf(&gdot[128 + blockIdx.x], gn);
                astf(&gdot[128 + 64 + blockIdx.x], dn);
            }
        }
        gp = gam; ap = alpha;
        flag_bar<false>(slots, tgt++);
    }

    // ---- k = 6: finalize (only p,x updates are live) ----
    {
        if (threadIdx.x < 64) {
            const float* dbase = gdot + 128;   // (6-1)&1 = 1
            float g0 = aldf(&dbase[lane]);
            float d0 = aldf(&dbase[64 + lane]);
            bfly2(g0, d0);
            if (threadIdx.x == 0) { sd[0] = g0; sd[1] = d0; }
        }
        __syncthreads();
        float gam = sd[0], del = sd[1];
        float beta  = (gp != 0.f) ? gam / gp : 0.f;
        float den   = del - beta * gam / ((ap != 0.f) ? ap : 1.f);
        float alpha = (den != 0.f) ? gam / den : 0.f;

        if (ownval) {
#pragma unroll
            for (int j = 0; j < 3; j++) {
                pO[j] = uO[j] + beta * pO[j];
                xO[j] += alpha * pO[j];
            }
#pragma unroll
            for (int j = 0; j < 3; j++) xout[3*own+j] = xO[j];
        }
    }
}

extern "C" void kernel_launch(void* const* d_in, const int* in_sizes, int n_in,
                              void* d_out, int out_size, void* d_ws, size_t ws_size,
                              hipStream_t stream) {
    const float* theta = (const float*)d_in[0];
    const float* delta = (const float*)d_in[1];
    const float* ra    = (const float*)d_in[2];
    const float* rs    = (const float*)d_in[3];
    const float* rv    = (const float*)d_in[4];
    const float* vol   = (const float*)d_in[5];
    const float* b     = (const float*)d_in[6];
    const int* tets    = (const int*)d_in[7];
    const int* boundary = (const int*)d_in[8];
    float* x = (float*)d_out;
    float* ws = (float*)d_ws;

    hipMemsetAsync(ws, 0, WS_WORDS * sizeof(float), stream);
    pcg_kernel<<<dim3(NBLK), dim3(NTHR), 0, stream>>>(theta, delta, ra, rs, rv, vol, b,
                                                      tets, boundary, x, ws);
}

// Round 22
// 92.676 us; speedup vs baseline: 3.0054x; 1.1380x over previous
//
#include <hip/hip_runtime.h>

#define M_TETS 10240
#define N_NODES 2048
#define NBUF 5
#define NBLK 32
#define NTHR 320
#define SPIN_CAP 50000000

typedef float f32x4 __attribute__((ext_vector_type(4)));

// ws float offsets (16B node stride)
#define BUFW 8192                          // 2048 nodes x 4 floats
#define OFF_VAL   12288                    // blk6: 6*2048 floats at 0
#define OFF_GDOT  (OFF_VAL + NBUF * BUFW)  // ring of NBUF buffers (0..4)
#define OFF_SLOT  (OFF_GDOT + 256)         // gdot: 2 sets x 2 comps x 64
#define WS_WORDS  (OFF_SLOT + 32)

// log(500), log(10000)
__device__ __constant__ float LOG_A_MIN_C = 6.2146080984221914f;
__device__ __constant__ float LOG_A_MAX_C = 9.2103403719761836f;

__device__ __forceinline__ void rel_fence() { __builtin_amdgcn_fence(__ATOMIC_RELEASE, "agent"); }
__device__ __forceinline__ void acq_fence() { __builtin_amdgcn_fence(__ATOMIC_ACQUIRE, "agent"); }
__device__ __forceinline__ unsigned aldu(const unsigned* p) {
    return __hip_atomic_load(p, __ATOMIC_RELAXED, __HIP_MEMORY_SCOPE_AGENT);
}
__device__ __forceinline__ float aldf(const float* p) {
    return __hip_atomic_load(p, __ATOMIC_RELAXED, __HIP_MEMORY_SCOPE_AGENT);
}
__device__ __forceinline__ void astf(float* p, float v) {
    __hip_atomic_store(p, v, __ATOMIC_RELAXED, __HIP_MEMORY_SCOPE_AGENT);
}
__device__ __forceinline__ void astu(unsigned* p, unsigned v) {
    __hip_atomic_store(p, v, __ATOMIC_RELAXED, __HIP_MEMORY_SCOPE_AGENT);
}

// coherence-point 16B load (R12/R14-proven: observes remote agent-atomic
// stores across XCDs with no fences)
__device__ __forceinline__ f32x4 vload4(const float* p) {
    return *(volatile const f32x4*)p;
}

// Flag barrier. FULL=true: full release/acquire fences (setup only).
// FULL=false: fence-free — in-loop writes are all agent atomics (performed at
// the coherence point); release ordering = s_waitcnt vmcnt(0) before the flag
// store; reads after the barrier use volatile/atomic ops, so no inv needed.
template<bool FULL>
__device__ __forceinline__ void flag_bar(unsigned* slots, unsigned tgt) {
    if (FULL) rel_fence();
    else asm volatile("s_waitcnt vmcnt(0)" ::: "memory");
    __syncthreads();
    if (threadIdx.x == 0) astu(&slots[blockIdx.x], tgt);
    if (threadIdx.x < NBLK) {
        int guard = 0;
        while (aldu(&slots[threadIdx.x]) < tgt && ++guard < SPIN_CAP) {}
    }
    __syncthreads();
    if (FULL) acq_fence();
    else asm volatile("" ::: "memory");
}

__device__ __forceinline__ void bfly2(float& a, float& b) {
#pragma unroll
    for (int off = 32; off > 0; off >>= 1) {
        a += __shfl_xor(a, off);
        b += __shfl_xor(b, off);
    }
}

// symmetric 3x3 apply: s6 = [00,01,02,11,12,22]
__device__ __forceinline__ void sym_apply(const float* s6, const float* v, float* out) {
    out[0] = s6[0]*v[0] + s6[1]*v[1] + s6[2]*v[2];
    out[1] = s6[1]*v[0] + s6[3]*v[1] + s6[4]*v[2];
    out[2] = s6[2]*v[0] + s6[4]*v[1] + s6[5]*v[2];
}

__device__ __forceinline__ void sym_inv(const float* s, float* o) {
    float a = s[0], b = s[1], c = s[2], d = s[3], e = s[4], f = s[5];
    float C00 = d*f - e*e, C01 = c*e - b*f, C02 = b*e - c*d;
    float id = 1.0f / (a*C00 + b*C01 + c*C02);
    o[0] = C00*id; o[1] = C01*id; o[2] = C02*id;
    o[3] = (a*f - c*c)*id; o[4] = (b*c - a*e)*id; o[5] = (a*d - b*b)*id;
}

__global__ void __launch_bounds__(NTHR, 1) pcg_kernel(
    const float* __restrict__ theta, const float* __restrict__ delta,
    const float* __restrict__ ra, const float* __restrict__ rs, const float* __restrict__ rv,
    const float* __restrict__ vol, const float* __restrict__ bvec,
    const int* __restrict__ tets, const int* __restrict__ boundary,
    float* __restrict__ xout, float* __restrict__ ws)
{
    const int tid = blockIdx.x * NTHR + threadIdx.x;   // element id, 10240 total
    const int lane = threadIdx.x & 63;
    __shared__ float sd[2];

    float*    blk6  = ws;
    float*    val   = ws + OFF_VAL;
    float*    gdot  = ws + OFF_GDOT;
    unsigned* slots = (unsigned*)(ws + OFF_SLOT);

    // ---- element data -> registers (ws pre-zeroed by hipMemsetAsync) ----
    float A[3][12], S[3][12], V[12];
    int nd4[4];
    float cae, cse, cve;
    {
        const int e = tid;
#pragma unroll
        for (int a = 0; a < 3; a++)
#pragma unroll
            for (int i = 0; i < 12; i++) {
                A[a][i] = ra[e * 36 + a * 12 + i];
                S[a][i] = rs[e * 36 + a * 12 + i];
            }
#pragma unroll
        for (int i = 0; i < 12; i++) V[i] = rv[e * 12 + i];
        const int4 t = reinterpret_cast<const int4*>(tets)[e];
        nd4[0] = t.x; nd4[1] = t.y; nd4[2] = t.z; nd4[3] = t.w;
        float la = theta[0] + delta[e];
        la = fminf(fmaxf(la, LOG_A_MIN_C), LOG_A_MAX_C);
        float al = expf(la);
        float v = vol[e];
        cae = v * al; cse = 2.0f * v * al; cve = 8.0f * v * al;
    }

    auto matvec = [&](const float* pe, float* y) {
#pragma unroll
        for (int t = 0; t < 12; t++) y[t] = 0.f;
#pragma unroll
        for (int a = 0; a < 3; a++) {
            float qa = 0.f, qs = 0.f;
#pragma unroll
            for (int t = 0; t < 12; t++) { qa += A[a][t] * pe[t]; qs += S[a][t] * pe[t]; }
            qa *= cae; qs *= cse;
#pragma unroll
            for (int t = 0; t < 12; t++) y[t] += qa * A[a][t] + qs * S[a][t];
        }
        float qv = 0.f;
#pragma unroll
        for (int t = 0; t < 12; t++) qv += V[t] * pe[t];
        qv *= cve;
#pragma unroll
        for (int t = 0; t < 12; t++) y[t] += qv * V[t];
    };

    // ---- S1: accumulate symmetric per-node 3x3 blocks of K ----
#pragma unroll
    for (int k = 0; k < 4; k++) {
        float b6[6] = {0,0,0,0,0,0};
#pragma unroll
        for (int a = 0; a < 3; a++) {
            float x0 = A[a][3*k], x1 = A[a][3*k+1], x2 = A[a][3*k+2];
            float s0 = S[a][3*k], s1 = S[a][3*k+1], s2 = S[a][3*k+2];
            b6[0] += cae*x0*x0 + cse*s0*s0;
            b6[1] += cae*x0*x1 + cse*s0*s1;
            b6[2] += cae*x0*x2 + cse*s0*s2;
            b6[3] += cae*x1*x1 + cse*s1*s1;
            b6[4] += cae*x1*x2 + cse*s1*s2;
            b6[5] += cae*x2*x2 + cse*s2*s2;
        }
        float v0 = V[3*k], v1 = V[3*k+1], v2 = V[3*k+2];
        b6[0] += cve*v0*v0; b6[1] += cve*v0*v1; b6[2] += cve*v0*v2;
        b6[3] += cve*v1*v1; b6[4] += cve*v1*v2; b6[5] += cve*v2*v2;
#pragma unroll
        for (int j = 0; j < 6; j++) atomicAdd(&blk6[nd4[k]*6 + j], b6[j]);
    }
    flag_bar<true>(slots, 1);

    // ---- local inverses: elements (masked, per node) and owners ----
    float ib[4][6], nmask4[4];
#pragma unroll
    for (int k = 0; k < 4; k++) {
        float bm = boundary[nd4[k]] ? 0.f : 1.f;
        nmask4[k] = bm;
        float s6[6];
#pragma unroll
        for (int j = 0; j < 6; j++) s6[j] = blk6[nd4[k]*6 + j];
        float iv[6];
        sym_inv(s6, iv);
#pragma unroll
        for (int j = 0; j < 6; j++) ib[k][j] = iv[j] * bm;
    }

    const int own = blockIdx.x * 64 + threadIdx.x;   // exact: 32*64 = 2048
    const bool ownval = (threadIdx.x < 64);
    float iO[6] = {0,0,0,0,0,0};
    float maskO = 0.f;
    float xO[3]={0,0,0}, rO[3]={0,0,0}, uO[3]={0,0,0}, wO[3]={0,0,0}, mO[3]={0,0,0};
    float zO[3]={0,0,0}, qO[3]={0,0,0}, pO[3]={0,0,0}, sO[3]={0,0,0};
    if (ownval) {
        maskO = boundary[own] ? 0.f : 1.f;
        float s6[6];
#pragma unroll
        for (int j = 0; j < 6; j++) s6[j] = blk6[own*6 + j];
        float iv[6];
        sym_inv(s6, iv);
#pragma unroll
        for (int j = 0; j < 6; j++) iO[j] = iv[j] * maskO;
#pragma unroll
        for (int j = 0; j < 3; j++) rO[j] = bvec[3*own+j] * maskO;
        sym_apply(iO, rO, uO);
    }

    // ---- phase -1: scatter A*u0 into ring[0] ----
    {
        float u0e[12];
#pragma unroll
        for (int k = 0; k < 4; k++) {
            float bb[3] = { bvec[3*nd4[k]], bvec[3*nd4[k]+1], bvec[3*nd4[k]+2] };
            sym_apply(ib[k], bb, &u0e[3*k]);
        }
        float y[12];
        matvec(u0e, y);
        float* v0 = val;                     // ring[0]
#pragma unroll
        for (int kk = 0; kk < 4; kk++)
#pragma unroll
            for (int c = 0; c < 3; c++) atomicAdd(&v0[4*nd4[kk]+c], y[3*kk+c]);
    }
    flag_bar<false>(slots, 2);

    // ---- phase 0: consume ring[0] (w0); init replicas/owner; scatter A*m0 -> ring[1] ----
    float w_e[12], z_e[12];
    {
        const float* vR = val;               // ring[0]
#pragma unroll
        for (int kk = 0; kk < 4; kk++) {
            f32x4 t = vload4(&vR[4*nd4[kk]]);
            w_e[3*kk]   = t[0] * nmask4[kk];
            w_e[3*kk+1] = t[1] * nmask4[kk];
            w_e[3*kk+2] = t[2] * nmask4[kk];
            z_e[3*kk] = 0.f; z_e[3*kk+1] = 0.f; z_e[3*kk+2] = 0.f;
        }
        float me[12];
#pragma unroll
        for (int kk = 0; kk < 4; kk++) sym_apply(ib[kk], &w_e[3*kk], &me[3*kk]);
        float y[12];
        matvec(me, y);
        float* vS = val + BUFW;              // ring[1]
#pragma unroll
        for (int kk = 0; kk < 4; kk++)
#pragma unroll
            for (int c = 0; c < 3; c++) atomicAdd(&vS[4*nd4[kk]+c], y[3*kk+c]);

        if (ownval) {
            float gn = 0.f, dn = 0.f;
            f32x4 t = vload4(&vR[4*own]);
            wO[0] = t[0] * maskO; wO[1] = t[1] * maskO; wO[2] = t[2] * maskO;
            sym_apply(iO, wO, mO);
#pragma unroll
            for (int j = 0; j < 3; j++) {
                gn += rO[j]*uO[j]; dn += wO[j]*uO[j];
            }
            bfly2(gn, dn);
            if (threadIdx.x == 0) {
                astf(&gdot[blockIdx.x], gn);
                astf(&gdot[64 + blockIdx.x], dn);
            }
        }
    }
    flag_bar<false>(slots, 3);

    // ---- full iterations k = 1..3 (scatter ring[k+1], publish dots(k)) ----
    float gp = 1.f, ap = 1.f;
    unsigned tgt = 4;

    for (int k = 1; k <= 3; k++) {
        const float* vR = val + k * BUFW;

        // gather n early (coherence point; overlaps dot completion)
        float ne[12];
#pragma unroll
        for (int kk = 0; kk < 4; kk++) {
            f32x4 t = vload4(&vR[4*nd4[kk]]);
            ne[3*kk]   = t[0] * nmask4[kk];
            ne[3*kk+1] = t[1] * nmask4[kk];
            ne[3*kk+2] = t[2] * nmask4[kk];
        }
        float nO[3] = {0,0,0};
        if (ownval) {
            f32x4 t = vload4(&vR[4*own]);
            nO[0] = t[0] * maskO; nO[1] = t[1] * maskO; nO[2] = t[2] * maskO;
        }

        // cross-block dot completion (wave 0; slots 32..63 are zero-padding)
        if (threadIdx.x < 64) {
            const float* dbase = gdot + ((k - 1) & 1) * 128;
            float g0 = aldf(&dbase[lane]);
            float d0 = aldf(&dbase[64 + lane]);
            bfly2(g0, d0);
            if (threadIdx.x == 0) { sd[0] = g0; sd[1] = d0; }
        }
        __syncthreads();
        float gam = sd[0], del = sd[1];

        float beta  = (k == 1) ? 0.f : ((gp != 0.f) ? gam / gp : 0.f);
        float den   = (k == 1) ? del : (del - beta * gam / ((ap != 0.f) ? ap : 1.f));
        float alpha = (den != 0.f) ? gam / den : 0.f;

        // element replica update + matvec + scatter into ring[k+1]
        {
#pragma unroll
            for (int t = 0; t < 12; t++) {
                z_e[t] = ne[t] + beta * z_e[t];
                w_e[t] -= alpha * z_e[t];
            }
            float me[12];
#pragma unroll
            for (int kk = 0; kk < 4; kk++) sym_apply(ib[kk], &w_e[3*kk], &me[3*kk]);
            float y[12];
            matvec(me, y);
            float* vS = val + (k + 1) * BUFW;
#pragma unroll
            for (int kk = 0; kk < 4; kk++)
#pragma unroll
                for (int c = 0; c < 3; c++) atomicAdd(&vS[4*nd4[kk]+c], y[3*kk+c]);
        }

        // owner recurrences + dot publish
        if (ownval) {
            float gn = 0.f, dn = 0.f;
#pragma unroll
            for (int j = 0; j < 3; j++) {
                zO[j] = nO[j] + beta * zO[j];
                qO[j] = mO[j] + beta * qO[j];
                pO[j] = uO[j] + beta * pO[j];
                sO[j] = wO[j] + beta * sO[j];
                xO[j] += alpha * pO[j];
                rO[j] -= alpha * sO[j];
                uO[j] -= alpha * qO[j];
                wO[j] -= alpha * zO[j];
            }
            sym_apply(iO, wO, mO);
#pragma unroll
            for (int j = 0; j < 3; j++) {
                gn += rO[j]*uO[j]; dn += wO[j]*uO[j];
            }
            bfly2(gn, dn);
            float* gd_pub = gdot + (k & 1) * 128;
            if (threadIdx.x == 0) {
                astf(&gd_pub[blockIdx.x], gn);
                astf(&gd_pub[64 + blockIdx.x], dn);
            }
        }

        gp = gam; ap = alpha;
        flag_bar<false>(slots, tgt++);
    }

    // ---- k = 4: owner-only (element scatter would feed only dead state) ----
    {
        // dot completion for dots(3) (set 1)
        if (threadIdx.x < 64) {
            const float* dbase = gdot + 128;   // (4-1)&1 = 1
            float g0 = aldf(&dbase[lane]);
            float d0 = aldf(&dbase[64 + lane]);
            bfly2(g0, d0);
            if (threadIdx.x == 0) { sd[0] = g0; sd[1] = d0; }
        }
        __syncthreads();
        float gam = sd[0], del = sd[1];
        float beta  = (gp != 0.f) ? gam / gp : 0.f;
        float den   = del - beta * gam / ((ap != 0.f) ? ap : 1.f);
        float alpha = (den != 0.f) ? gam / den : 0.f;

        if (ownval) {
            f32x4 t = vload4(&val[4 * BUFW + 4*own]);
            float nO[3] = { t[0] * maskO, t[1] * maskO, t[2] * maskO };
            float gn = 0.f, dn = 0.f;
#pragma unroll
            for (int j = 0; j < 3; j++) {
                zO[j] = nO[j] + beta * zO[j];
                qO[j] = mO[j] + beta * qO[j];
                pO[j] = uO[j] + beta * pO[j];
                sO[j] = wO[j] + beta * sO[j];
                xO[j] += alpha * pO[j];
                rO[j] -= alpha * sO[j];
                uO[j] -= alpha * qO[j];
                wO[j] -= alpha * zO[j];
            }
#pragma unroll
            for (int j = 0; j < 3; j++) {
                gn += rO[j]*uO[j]; dn += wO[j]*uO[j];
            }
            bfly2(gn, dn);
            if (threadIdx.x == 0) {          // publish dots(4) -> set 0
                astf(&gdot[blockIdx.x], gn);
                astf(&gdot[64 + blockIdx.x], dn);
            }
        }
        gp = gam; ap = alpha;
        flag_bar<false>(slots, tgt++);
    }

    // ---- k = 5: finalize (only p,x updates are live) ----
    {
        if (threadIdx.x < 64) {
            const float* dbase = gdot;         // (5-1)&1 = 0
            float g0 = aldf(&dbase[lane]);
            float d0 = aldf(&dbase[64 + lane]);
            bfly2(g0, d0);
            if (threadIdx.x == 0) { sd[0] = g0; sd[1] = d0; }
        }
        __syncthreads();
        float gam = sd[0], del = sd[1];
        float beta  = (gp != 0.f) ? gam / gp : 0.f;
        float den   = del - beta * gam / ((ap != 0.f) ? ap : 1.f);
        float alpha = (den != 0.f) ? gam / den : 0.f;

        if (ownval) {
#pragma unroll
            for (int j = 0; j < 3; j++) {
                pO[j] = uO[j] + beta * pO[j];
                xO[j] += alpha * pO[j];
            }
#pragma unroll
            for (int j = 0; j < 3; j++) xout[3*own+j] = xO[j];
        }
    }
}

extern "C" void kernel_launch(void* const* d_in, const int* in_sizes, int n_in,
                              void* d_out, int out_size, void* d_ws, size_t ws_size,
                              hipStream_t stream) {
    const float* theta = (const float*)d_in[0];
    const float* delta = (const float*)d_in[1];
    const float* ra    = (const float*)d_in[2];
    const float* rs    = (const float*)d_in[3];
    const float* rv    = (const float*)d_in[4];
    const float* vol   = (const float*)d_in[5];
    const float* b     = (const float*)d_in[6];
    const int* tets    = (const int*)d_in[7];
    const int* boundary = (const int*)d_in[8];
    float* x = (float*)d_out;
    float* ws = (float*)d_ws;

    hipMemsetAsync(ws, 0, WS_WORDS * sizeof(float), stream);
    pcg_kernel<<<dim3(NBLK), dim3(NTHR), 0, stream>>>(theta, delta, ra, rs, rv, vol, b,
                                                      tets, boundary, x, ws);
}

// Round 23
// 81.605 us; speedup vs baseline: 3.4131x; 1.1357x over previous
//
#include <hip/hip_runtime.h>

#define M_TETS 10240
#define N_NODES 2048
#define NBUF 4
#define NBLK 32
#define NTHR 320
#define SPIN_CAP 50000000

typedef float f32x4 __attribute__((ext_vector_type(4)));

// ws float offsets (16B node stride)
#define BUFW 8192                          // 2048 nodes x 4 floats
#define OFF_VAL   12288                    // blk6: 6*2048 floats at 0
#define OFF_GDOT  (OFF_VAL + NBUF * BUFW)  // ring of NBUF buffers (0..3)
#define OFF_SLOT  (OFF_GDOT + 256)         // gdot: 2 sets x 2 comps x 64
#define WS_WORDS  (OFF_SLOT + 32)

// log(500), log(10000)
__device__ __constant__ float LOG_A_MIN_C = 6.2146080984221914f;
__device__ __constant__ float LOG_A_MAX_C = 9.2103403719761836f;

__device__ __forceinline__ void rel_fence() { __builtin_amdgcn_fence(__ATOMIC_RELEASE, "agent"); }
__device__ __forceinline__ void acq_fence() { __builtin_amdgcn_fence(__ATOMIC_ACQUIRE, "agent"); }
__device__ __forceinline__ unsigned aldu(const unsigned* p) {
    return __hip_atomic_load(p, __ATOMIC_RELAXED, __HIP_MEMORY_SCOPE_AGENT);
}
__device__ __forceinline__ float aldf(const float* p) {
    return __hip_atomic_load(p, __ATOMIC_RELAXED, __HIP_MEMORY_SCOPE_AGENT);
}
__device__ __forceinline__ void astf(float* p, float v) {
    __hip_atomic_store(p, v, __ATOMIC_RELAXED, __HIP_MEMORY_SCOPE_AGENT);
}
__device__ __forceinline__ void astu(unsigned* p, unsigned v) {
    __hip_atomic_store(p, v, __ATOMIC_RELAXED, __HIP_MEMORY_SCOPE_AGENT);
}

// coherence-point 16B load (R12/R14-proven: observes remote agent-atomic
// stores across XCDs with no fences)
__device__ __forceinline__ f32x4 vload4(const float* p) {
    return *(volatile const f32x4*)p;
}

// Flag barrier. FULL=true: full release/acquire fences (setup only).
// FULL=false: fence-free — in-loop writes are all agent atomics (performed at
// the coherence point); release ordering = s_waitcnt vmcnt(0) before the flag
// store; reads after the barrier use volatile/atomic ops, so no inv needed.
template<bool FULL>
__device__ __forceinline__ void flag_bar(unsigned* slots, unsigned tgt) {
    if (FULL) rel_fence();
    else asm volatile("s_waitcnt vmcnt(0)" ::: "memory");
    __syncthreads();
    if (threadIdx.x == 0) astu(&slots[blockIdx.x], tgt);
    if (threadIdx.x < NBLK) {
        int guard = 0;
        while (aldu(&slots[threadIdx.x]) < tgt && ++guard < SPIN_CAP) {}
    }
    __syncthreads();
    if (FULL) acq_fence();
    else asm volatile("" ::: "memory");
}

__device__ __forceinline__ void bfly2(float& a, float& b) {
#pragma unroll
    for (int off = 32; off > 0; off >>= 1) {
        a += __shfl_xor(a, off);
        b += __shfl_xor(b, off);
    }
}

// symmetric 3x3 apply: s6 = [00,01,02,11,12,22]
__device__ __forceinline__ void sym_apply(const float* s6, const float* v, float* out) {
    out[0] = s6[0]*v[0] + s6[1]*v[1] + s6[2]*v[2];
    out[1] = s6[1]*v[0] + s6[3]*v[1] + s6[4]*v[2];
    out[2] = s6[2]*v[0] + s6[4]*v[1] + s6[5]*v[2];
}

__device__ __forceinline__ void sym_inv(const float* s, float* o) {
    float a = s[0], b = s[1], c = s[2], d = s[3], e = s[4], f = s[5];
    float C00 = d*f - e*e, C01 = c*e - b*f, C02 = b*e - c*d;
    float id = 1.0f / (a*C00 + b*C01 + c*C02);
    o[0] = C00*id; o[1] = C01*id; o[2] = C02*id;
    o[3] = (a*f - c*c)*id; o[4] = (b*c - a*e)*id; o[5] = (a*d - b*b)*id;
}

__global__ void __launch_bounds__(NTHR, 1) pcg_kernel(
    const float* __restrict__ theta, const float* __restrict__ delta,
    const float* __restrict__ ra, const float* __restrict__ rs, const float* __restrict__ rv,
    const float* __restrict__ vol, const float* __restrict__ bvec,
    const int* __restrict__ tets, const int* __restrict__ boundary,
    float* __restrict__ xout, float* __restrict__ ws)
{
    const int tid = blockIdx.x * NTHR + threadIdx.x;   // element id, 10240 total
    const int lane = threadIdx.x & 63;
    __shared__ float sd[2];

    float*    blk6  = ws;
    float*    val   = ws + OFF_VAL;
    float*    gdot  = ws + OFF_GDOT;
    unsigned* slots = (unsigned*)(ws + OFF_SLOT);

    // ---- element data -> registers (ws pre-zeroed by hipMemsetAsync) ----
    float A[3][12], S[3][12], V[12];
    int nd4[4];
    float cae, cse, cve;
    {
        const int e = tid;
#pragma unroll
        for (int a = 0; a < 3; a++)
#pragma unroll
            for (int i = 0; i < 12; i++) {
                A[a][i] = ra[e * 36 + a * 12 + i];
                S[a][i] = rs[e * 36 + a * 12 + i];
            }
#pragma unroll
        for (int i = 0; i < 12; i++) V[i] = rv[e * 12 + i];
        const int4 t = reinterpret_cast<const int4*>(tets)[e];
        nd4[0] = t.x; nd4[1] = t.y; nd4[2] = t.z; nd4[3] = t.w;
        float la = theta[0] + delta[e];
        la = fminf(fmaxf(la, LOG_A_MIN_C), LOG_A_MAX_C);
        float al = expf(la);
        float v = vol[e];
        cae = v * al; cse = 2.0f * v * al; cve = 8.0f * v * al;
    }

    auto matvec = [&](const float* pe, float* y) {
#pragma unroll
        for (int t = 0; t < 12; t++) y[t] = 0.f;
#pragma unroll
        for (int a = 0; a < 3; a++) {
            float qa = 0.f, qs = 0.f;
#pragma unroll
            for (int t = 0; t < 12; t++) { qa += A[a][t] * pe[t]; qs += S[a][t] * pe[t]; }
            qa *= cae; qs *= cse;
#pragma unroll
            for (int t = 0; t < 12; t++) y[t] += qa * A[a][t] + qs * S[a][t];
        }
        float qv = 0.f;
#pragma unroll
        for (int t = 0; t < 12; t++) qv += V[t] * pe[t];
        qv *= cve;
#pragma unroll
        for (int t = 0; t < 12; t++) y[t] += qv * V[t];
    };

    // ---- S1: accumulate symmetric per-node 3x3 blocks of K ----
#pragma unroll
    for (int k = 0; k < 4; k++) {
        float b6[6] = {0,0,0,0,0,0};
#pragma unroll
        for (int a = 0; a < 3; a++) {
            float x0 = A[a][3*k], x1 = A[a][3*k+1], x2 = A[a][3*k+2];
            float s0 = S[a][3*k], s1 = S[a][3*k+1], s2 = S[a][3*k+2];
            b6[0] += cae*x0*x0 + cse*s0*s0;
            b6[1] += cae*x0*x1 + cse*s0*s1;
            b6[2] += cae*x0*x2 + cse*s0*s2;
            b6[3] += cae*x1*x1 + cse*s1*s1;
            b6[4] += cae*x1*x2 + cse*s1*s2;
            b6[5] += cae*x2*x2 + cse*s2*s2;
        }
        float v0 = V[3*k], v1 = V[3*k+1], v2 = V[3*k+2];
        b6[0] += cve*v0*v0; b6[1] += cve*v0*v1; b6[2] += cve*v0*v2;
        b6[3] += cve*v1*v1; b6[4] += cve*v1*v2; b6[5] += cve*v2*v2;
#pragma unroll
        for (int j = 0; j < 6; j++) atomicAdd(&blk6[nd4[k]*6 + j], b6[j]);
    }
    flag_bar<true>(slots, 1);

    // ---- local inverses: elements (masked, per node) and owners ----
    float ib[4][6], nmask4[4];
#pragma unroll
    for (int k = 0; k < 4; k++) {
        float bm = boundary[nd4[k]] ? 0.f : 1.f;
        nmask4[k] = bm;
        float s6[6];
#pragma unroll
        for (int j = 0; j < 6; j++) s6[j] = blk6[nd4[k]*6 + j];
        float iv[6];
        sym_inv(s6, iv);
#pragma unroll
        for (int j = 0; j < 6; j++) ib[k][j] = iv[j] * bm;
    }

    const int own = blockIdx.x * 64 + threadIdx.x;   // exact: 32*64 = 2048
    const bool ownval = (threadIdx.x < 64);
    float iO[6] = {0,0,0,0,0,0};
    float maskO = 0.f;
    float xO[3]={0,0,0}, rO[3]={0,0,0}, uO[3]={0,0,0}, wO[3]={0,0,0}, mO[3]={0,0,0};
    float zO[3]={0,0,0}, qO[3]={0,0,0}, pO[3]={0,0,0}, sO[3]={0,0,0};
    if (ownval) {
        maskO = boundary[own] ? 0.f : 1.f;
        float s6[6];
#pragma unroll
        for (int j = 0; j < 6; j++) s6[j] = blk6[own*6 + j];
        float iv[6];
        sym_inv(s6, iv);
#pragma unroll
        for (int j = 0; j < 6; j++) iO[j] = iv[j] * maskO;
#pragma unroll
        for (int j = 0; j < 3; j++) rO[j] = bvec[3*own+j] * maskO;
        sym_apply(iO, rO, uO);
    }

    // ---- phase -1: scatter A*u0 into ring[0] ----
    {
        float u0e[12];
#pragma unroll
        for (int k = 0; k < 4; k++) {
            float bb[3] = { bvec[3*nd4[k]], bvec[3*nd4[k]+1], bvec[3*nd4[k]+2] };
            sym_apply(ib[k], bb, &u0e[3*k]);
        }
        float y[12];
        matvec(u0e, y);
        float* v0 = val;                     // ring[0]
#pragma unroll
        for (int kk = 0; kk < 4; kk++)
#pragma unroll
            for (int c = 0; c < 3; c++) atomicAdd(&v0[4*nd4[kk]+c], y[3*kk+c]);
    }
    flag_bar<false>(slots, 2);

    // ---- phase 0: consume ring[0] (w0); init replicas/owner; scatter A*m0 -> ring[1] ----
    float w_e[12], z_e[12];
    {
        const float* vR = val;               // ring[0]
#pragma unroll
        for (int kk = 0; kk < 4; kk++) {
            f32x4 t = vload4(&vR[4*nd4[kk]]);
            w_e[3*kk]   = t[0] * nmask4[kk];
            w_e[3*kk+1] = t[1] * nmask4[kk];
            w_e[3*kk+2] = t[2] * nmask4[kk];
            z_e[3*kk] = 0.f; z_e[3*kk+1] = 0.f; z_e[3*kk+2] = 0.f;
        }
        float me[12];
#pragma unroll
        for (int kk = 0; kk < 4; kk++) sym_apply(ib[kk], &w_e[3*kk], &me[3*kk]);
        float y[12];
        matvec(me, y);
        float* vS = val + BUFW;              // ring[1]
#pragma unroll
        for (int kk = 0; kk < 4; kk++)
#pragma unroll
            for (int c = 0; c < 3; c++) atomicAdd(&vS[4*nd4[kk]+c], y[3*kk+c]);

        if (ownval) {
            float gn = 0.f, dn = 0.f;
            f32x4 t = vload4(&vR[4*own]);
            wO[0] = t[0] * maskO; wO[1] = t[1] * maskO; wO[2] = t[2] * maskO;
            sym_apply(iO, wO, mO);
#pragma unroll
            for (int j = 0; j < 3; j++) {
                gn += rO[j]*uO[j]; dn += wO[j]*uO[j];
            }
            bfly2(gn, dn);
            if (threadIdx.x == 0) {
                astf(&gdot[blockIdx.x], gn);
                astf(&gdot[64 + blockIdx.x], dn);
            }
        }
    }
    flag_bar<false>(slots, 3);

    // ---- full iterations k = 1..2 (scatter ring[k+1], publish dots(k)) ----
    float gp = 1.f, ap = 1.f;
    unsigned tgt = 4;

    for (int k = 1; k <= 2; k++) {
        const float* vR = val + k * BUFW;

        // gather n early (coherence point; overlaps dot completion)
        float ne[12];
#pragma unroll
        for (int kk = 0; kk < 4; kk++) {
            f32x4 t = vload4(&vR[4*nd4[kk]]);
            ne[3*kk]   = t[0] * nmask4[kk];
            ne[3*kk+1] = t[1] * nmask4[kk];
            ne[3*kk+2] = t[2] * nmask4[kk];
        }
        float nO[3] = {0,0,0};
        if (ownval) {
            f32x4 t = vload4(&vR[4*own]);
            nO[0] = t[0] * maskO; nO[1] = t[1] * maskO; nO[2] = t[2] * maskO;
        }

        // cross-block dot completion (wave 0; slots 32..63 are zero-padding)
        if (threadIdx.x < 64) {
            const float* dbase = gdot + ((k - 1) & 1) * 128;
            float g0 = aldf(&dbase[lane]);
            float d0 = aldf(&dbase[64 + lane]);
            bfly2(g0, d0);
            if (threadIdx.x == 0) { sd[0] = g0; sd[1] = d0; }
        }
        __syncthreads();
        float gam = sd[0], del = sd[1];

        float beta  = (k == 1) ? 0.f : ((gp != 0.f) ? gam / gp : 0.f);
        float den   = (k == 1) ? del : (del - beta * gam / ((ap != 0.f) ? ap : 1.f));
        float alpha = (den != 0.f) ? gam / den : 0.f;

        // element replica update + matvec + scatter into ring[k+1]
        {
#pragma unroll
            for (int t = 0; t < 12; t++) {
                z_e[t] = ne[t] + beta * z_e[t];
                w_e[t] -= alpha * z_e[t];
            }
            float me[12];
#pragma unroll
            for (int kk = 0; kk < 4; kk++) sym_apply(ib[kk], &w_e[3*kk], &me[3*kk]);
            float y[12];
            matvec(me, y);
            float* vS = val + (k + 1) * BUFW;
#pragma unroll
            for (int kk = 0; kk < 4; kk++)
#pragma unroll
                for (int c = 0; c < 3; c++) atomicAdd(&vS[4*nd4[kk]+c], y[3*kk+c]);
        }

        // owner recurrences + dot publish
        if (ownval) {
            float gn = 0.f, dn = 0.f;
#pragma unroll
            for (int j = 0; j < 3; j++) {
                zO[j] = nO[j] + beta * zO[j];
                qO[j] = mO[j] + beta * qO[j];
                pO[j] = uO[j] + beta * pO[j];
                sO[j] = wO[j] + beta * sO[j];
                xO[j] += alpha * pO[j];
                rO[j] -= alpha * sO[j];
                uO[j] -= alpha * qO[j];
                wO[j] -= alpha * zO[j];
            }
            sym_apply(iO, wO, mO);
#pragma unroll
            for (int j = 0; j < 3; j++) {
                gn += rO[j]*uO[j]; dn += wO[j]*uO[j];
            }
            bfly2(gn, dn);
            float* gd_pub = gdot + (k & 1) * 128;
            if (threadIdx.x == 0) {
                astf(&gd_pub[blockIdx.x], gn);
                astf(&gd_pub[64 + blockIdx.x], dn);
            }
        }

        gp = gam; ap = alpha;
        flag_bar<false>(slots, tgt++);
    }

    // ---- k = 3: owner-only (element scatter would feed only dead state) ----
    {
        // dot completion for dots(2) (set 0)
        if (threadIdx.x < 64) {
            const float* dbase = gdot;         // (3-1)&1 = 0
            float g0 = aldf(&dbase[lane]);
            float d0 = aldf(&dbase[64 + lane]);
            bfly2(g0, d0);
            if (threadIdx.x == 0) { sd[0] = g0; sd[1] = d0; }
        }
        __syncthreads();
        float gam = sd[0], del = sd[1];
        float beta  = (gp != 0.f) ? gam / gp : 0.f;
        float den   = del - beta * gam / ((ap != 0.f) ? ap : 1.f);
        float alpha = (den != 0.f) ? gam / den : 0.f;

        if (ownval) {
            f32x4 t = vload4(&val[3 * BUFW + 4*own]);
            float nO[3] = { t[0] * maskO, t[1] * maskO, t[2] * maskO };
            float gn = 0.f, dn = 0.f;
#pragma unroll
            for (int j = 0; j < 3; j++) {
                zO[j] = nO[j] + beta * zO[j];
                qO[j] = mO[j] + beta * qO[j];
                pO[j] = uO[j] + beta * pO[j];
                sO[j] = wO[j] + beta * sO[j];
                xO[j] += alpha * pO[j];
                rO[j] -= alpha * sO[j];
                uO[j] -= alpha * qO[j];
                wO[j] -= alpha * zO[j];
            }
#pragma unroll
            for (int j = 0; j < 3; j++) {
                gn += rO[j]*uO[j]; dn += wO[j]*uO[j];
            }
            bfly2(gn, dn);
            if (threadIdx.x == 0) {          // publish dots(3) -> set 1
                astf(&gdot[128 + blockIdx.x], gn);
                astf(&gdot[128 + 64 + blockIdx.x], dn);
            }
        }
        gp = gam; ap = alpha;
        flag_bar<false>(slots, tgt++);
    }

    // ---- k = 4: finalize (only p,x updates are live) ----
    {
        if (threadIdx.x < 64) {
            const float* dbase = gdot + 128;   // (4-1)&1 = 1
            float g0 = aldf(&dbase[lane]);
            float d0 = aldf(&dbase[64 + lane]);
            bfly2(g0, d0);
            if (threadIdx.x == 0) { sd[0] = g0; sd[1] = d0; }
        }
        __syncthreads();
        float gam = sd[0], del = sd[1];
        float beta  = (gp != 0.f) ? gam / gp : 0.f;
        float den   = del - beta * gam / ((ap != 0.f) ? ap : 1.f);
        float alpha = (den != 0.f) ? gam / den : 0.f;

        if (ownval) {
#pragma unroll
            for (int j = 0; j < 3; j++) {
                pO[j] = uO[j] + beta * pO[j];
                xO[j] += alpha * pO[j];
            }
#pragma unroll
            for (int j = 0; j < 3; j++) xout[3*own+j] = xO[j];
        }
    }
}

extern "C" void kernel_launch(void* const* d_in, const int* in_sizes, int n_in,
                              void* d_out, int out_size, void* d_ws, size_t ws_size,
                              hipStream_t stream) {
    const float* theta = (const float*)d_in[0];
    const float* delta = (const float*)d_in[1];
    const float* ra    = (const float*)d_in[2];
    const float* rs    = (const float*)d_in[3];
    const float* rv    = (const float*)d_in[4];
    const float* vol   = (const float*)d_in[5];
    const float* b     = (const float*)d_in[6];
    const int* tets    = (const int*)d_in[7];
    const int* boundary = (const int*)d_in[8];
    float* x = (float*)d_out;
    float* ws = (float*)d_ws;

    hipMemsetAsync(ws, 0, WS_WORDS * sizeof(float), stream);
    pcg_kernel<<<dim3(NBLK), dim3(NTHR), 0, stream>>>(theta, delta, ra, rs, rv, vol, b,
                                                      tets, boundary, x, ws);
}